// Round 2
// baseline (515.468 us; speedup 1.0000x reference)
//
#include <hip/hip_runtime.h>
#include <math.h>

#define NUM_CLASSES 80
#define F4_PER_ROW  20                 // 80 floats = 20 float4
#define ROWS_PER_BLOCK 128
#define THREADS 128
#define ROW_STRIDE 84                  // padded LDS row stride (words); conflict-free b128

constexpr float ALPHA = 0.25f;
constexpr float CENTER_W = 0.1f;
constexpr float EPS_GIOU = 1e-7f;

// ---------------------------------------------------------------------------
// Kernel 1: stage logits slab to LDS (coalesced), per-row losses, block-reduce
// ---------------------------------------------------------------------------
__global__ __launch_bounds__(THREADS) void hdm_loss_kernel(
    const float* __restrict__ cls_logits,   // (N, 80)
    const float* __restrict__ bbox_reg,     // (N, 4)
    const float* __restrict__ centerness,   // (N,)
    const float* __restrict__ gt_bboxes,    // (N, 4)
    const int*   __restrict__ gt_classes,   // (N,)
    double* __restrict__ partials,          // (gridDim.x, 3)
    int n)
{
    __shared__ float tile[ROWS_PER_BLOCK * ROW_STRIDE];   // 43008 B

    const int t = threadIdx.x;
    const int row_base = blockIdx.x * ROWS_PER_BLOCK;
    const int row = row_base + t;

    // ---- coalesced staging: slab = 128 rows * 20 float4 = 2560 float4 ----
    const int total_f4 = n * F4_PER_ROW;
    const int slab_base = row_base * F4_PER_ROW;
    const float4* src = (const float4*)cls_logits;
    #pragma unroll
    for (int k = 0; k < F4_PER_ROW; ++k) {
        const int F = k * THREADS + t;          // local float4 index in slab
        const int gF = slab_base + F;
        if (gF < total_f4) {
            const float4 v = src[gF];
            const int lrow = F / F4_PER_ROW;    // 0..127
            const int c4   = F % F4_PER_ROW;    // 0..19
            *(float4*)&tile[lrow * ROW_STRIDE + c4 * 4] = v;
        }
    }
    __syncthreads();

    float focal_t = 0.0f, giou_t = 0.0f, center_t = 0.0f;

    if (row < n) {
        // ---------------- focal loss (softmax from LDS) ----------------
        const float4* myrow = (const float4*)&tile[t * ROW_STRIDE];
        float m = -INFINITY;
        #pragma unroll
        for (int j = 0; j < F4_PER_ROW; ++j) {
            const float4 v = myrow[j];
            m = fmaxf(m, fmaxf(fmaxf(v.x, v.y), fmaxf(v.z, v.w)));
        }
        float s = 0.0f;
        #pragma unroll
        for (int j = 0; j < F4_PER_ROW; ++j) {
            const float4 v = myrow[j];
            s += __expf(v.x - m);
            s += __expf(v.y - m);
            s += __expf(v.z - m);
            s += __expf(v.w - m);
        }
        const int gc = gt_classes[row];
        const float xg = tile[t * ROW_STRIDE + gc];
        const float lse = m + __logf(s);
        const float ce  = lse - xg;
        const float pt  = __expf(-ce);
        const float omp = 1.0f - pt;
        focal_t = ALPHA * omp * omp * ce;

        // ---------------- GIoU loss ----------------
        const float4 p = ((const float4*)bbox_reg)[row];
        const float4 g = ((const float4*)gt_bboxes)[row];
        const float iw = fmaxf(fminf(p.z, g.z) - fmaxf(p.x, g.x), 0.0f);
        const float ih = fmaxf(fminf(p.w, g.w) - fmaxf(p.y, g.y), 0.0f);
        const float inter  = iw * ih;
        const float area_p = (p.z - p.x) * (p.w - p.y);
        const float area_g = (g.z - g.x) * (g.w - g.y);
        const float uni    = area_p + area_g - inter;
        const float iou    = inter / (uni + EPS_GIOU);
        const float cw = fmaxf(p.z, g.z) - fminf(p.x, g.x);
        const float ch = fmaxf(p.w, g.w) - fminf(p.y, g.y);
        const float area_c = cw * ch;
        const float giou = iou - (area_c - uni) / (area_c + EPS_GIOU);
        giou_t = 1.0f - giou;

        // ---------------- centerness loss: softplus(-c) ----------------
        const float c = centerness[row];
        center_t = fmaxf(-c, 0.0f) + log1pf(__expf(-fabsf(c)));
    }

    // ---------------- block reduction (double, 2 waves) ----------------
    double f = (double)focal_t, gi = (double)giou_t, ce_ = (double)center_t;
    #pragma unroll
    for (int off = 32; off > 0; off >>= 1) {
        f   += __shfl_down(f,   off, 64);
        gi  += __shfl_down(gi,  off, 64);
        ce_ += __shfl_down(ce_, off, 64);
    }
    __shared__ double sf[2], sg[2], sc[2];
    const int lane = t & 63;
    const int wave = t >> 6;
    if (lane == 0) { sf[wave] = f; sg[wave] = gi; sc[wave] = ce_; }
    __syncthreads();
    if (t == 0) {
        partials[blockIdx.x * 3 + 0] = sf[0] + sf[1];
        partials[blockIdx.x * 3 + 1] = sg[0] + sg[1];
        partials[blockIdx.x * 3 + 2] = sc[0] + sc[1];
    }
}

// ---------------------------------------------------------------------------
// Kernel 2: reduce partials, write the 4 output scalars
// ---------------------------------------------------------------------------
__global__ __launch_bounds__(256) void hdm_finalize_kernel(
    const double* __restrict__ partials, int nblocks, int n,
    float* __restrict__ out)
{
    double f = 0.0, g = 0.0, c = 0.0;
    for (int i = threadIdx.x; i < nblocks; i += 256) {
        f += partials[i * 3 + 0];
        g += partials[i * 3 + 1];
        c += partials[i * 3 + 2];
    }
    #pragma unroll
    for (int off = 32; off > 0; off >>= 1) {
        f += __shfl_down(f, off, 64);
        g += __shfl_down(g, off, 64);
        c += __shfl_down(c, off, 64);
    }
    __shared__ double sf[4], sg[4], sc[4];
    const int lane = threadIdx.x & 63;
    const int wave = threadIdx.x >> 6;
    if (lane == 0) { sf[wave] = f; sg[wave] = g; sc[wave] = c; }
    __syncthreads();
    if (threadIdx.x == 0) {
        double tf = 0.0, tg = 0.0, tc = 0.0;
        #pragma unroll
        for (int w = 0; w < 4; ++w) { tf += sf[w]; tg += sg[w]; tc += sc[w]; }
        const double inv_n = 1.0 / (double)n;
        const double focal_mean  = tf * inv_n;
        const double iou_mean    = tg * inv_n;
        const double center_mean = tc * inv_n;
        const double total = focal_mean + iou_mean + (double)CENTER_W * center_mean;
        out[0] = (float)total;
        out[1] = (float)focal_mean;
        out[2] = (float)iou_mean;
        out[3] = (float)center_mean;
    }
}

extern "C" void kernel_launch(void* const* d_in, const int* in_sizes, int n_in,
                              void* d_out, int out_size, void* d_ws, size_t ws_size,
                              hipStream_t stream) {
    const float* cls_logits = (const float*)d_in[0];
    const float* bbox_reg   = (const float*)d_in[1];
    const float* centerness = (const float*)d_in[2];
    const float* gt_bboxes  = (const float*)d_in[3];
    const int*   gt_classes = (const int*)d_in[4];
    float* out = (float*)d_out;

    const int n = in_sizes[2];                          // N
    const int nblocks = (n + ROWS_PER_BLOCK - 1) / ROWS_PER_BLOCK;   // 7813
    double* partials = (double*)d_ws;                   // nblocks*3*8B ≈ 188 KB

    hdm_loss_kernel<<<nblocks, THREADS, 0, stream>>>(
        cls_logits, bbox_reg, centerness, gt_bboxes, gt_classes, partials, n);
    hdm_finalize_kernel<<<1, 256, 0, stream>>>(partials, nblocks, n, out);
}

// Round 3
// 463.438 us; speedup vs baseline: 1.1123x; 1.1123x over previous
//
#include <hip/hip_runtime.h>
#include <math.h>

#define NUM_CLASSES 80
#define F4_PER_ROW  20                 // 80 floats = 20 float4
#define ROWS_PER_BLOCK 64
#define THREADS 256
#define F4_PER_SLAB (ROWS_PER_BLOCK * F4_PER_ROW)   // 1280
#define F4_PER_THREAD (F4_PER_SLAB / THREADS)       // 5
#define ROW_STRIDE 84                  // padded LDS row stride (words): (20*(lrow+q))%32 tiles all banks

constexpr float ALPHA = 0.25f;
constexpr float CENTER_W = 0.1f;
constexpr float EPS_GIOU = 1e-7f;

// ---------------------------------------------------------------------------
// Kernel 1: coalesced LDS staging, 4 threads per row, block-reduce
// ---------------------------------------------------------------------------
__global__ __launch_bounds__(THREADS) void hdm_loss_kernel(
    const float* __restrict__ cls_logits,   // (N, 80)
    const float* __restrict__ bbox_reg,     // (N, 4)
    const float* __restrict__ centerness,   // (N,)
    const float* __restrict__ gt_bboxes,    // (N, 4)
    const int*   __restrict__ gt_classes,   // (N,)
    double* __restrict__ partials,          // (gridDim.x, 3)
    int n)
{
    __shared__ float tile[ROWS_PER_BLOCK * ROW_STRIDE];   // 21504 B -> 7 blocks/CU

    const int t = threadIdx.x;
    const int row_base = blockIdx.x * ROWS_PER_BLOCK;

    // ---- coalesced staging: 1280 float4 per block, 5 per thread ----
    const int total_f4 = n * F4_PER_ROW;
    const int slab_base = row_base * F4_PER_ROW;
    const float4* src = (const float4*)cls_logits;
    float4 v[F4_PER_THREAD];
    #pragma unroll
    for (int k = 0; k < F4_PER_THREAD; ++k) {
        const int gF = slab_base + k * THREADS + t;
        v[k] = (gF < total_f4) ? src[gF] : make_float4(0.f, 0.f, 0.f, 0.f);
    }
    #pragma unroll
    for (int k = 0; k < F4_PER_THREAD; ++k) {
        const int F = k * THREADS + t;
        const int lrow = F / F4_PER_ROW;    // 0..63
        const int c4   = F % F4_PER_ROW;    // 0..19
        *(float4*)&tile[lrow * ROW_STRIDE + c4 * 4] = v[k];
    }
    __syncthreads();

    // ---- compute: quad (4 threads) per row ----
    const int lrow = t >> 2;                // 0..63
    const int q    = t & 3;                 // quarter of the row
    const int row  = row_base + lrow;
    const bool live = (row < n);

    // each thread's 20-float segment, one LDS read into registers
    float4 w[5];
    const float4* myseg = (const float4*)&tile[lrow * ROW_STRIDE + q * 20];
    #pragma unroll
    for (int j = 0; j < 5; ++j) w[j] = myseg[j];

    // segment max -> quad max
    float m = -INFINITY;
    #pragma unroll
    for (int j = 0; j < 5; ++j)
        m = fmaxf(m, fmaxf(fmaxf(w[j].x, w[j].y), fmaxf(w[j].z, w[j].w)));
    m = fmaxf(m, __shfl_xor(m, 1, 64));
    m = fmaxf(m, __shfl_xor(m, 2, 64));

    // segment sum-exp -> quad sum
    float s = 0.0f;
    #pragma unroll
    for (int j = 0; j < 5; ++j) {
        s += __expf(w[j].x - m);
        s += __expf(w[j].y - m);
        s += __expf(w[j].z - m);
        s += __expf(w[j].w - m);
    }
    s += __shfl_xor(s, 1, 64);
    s += __shfl_xor(s, 2, 64);

    float focal_t = 0.0f, giou_t = 0.0f, center_t = 0.0f;

    if (live && q == 0) {
        // ---------------- focal loss (leader lane of quad) ----------------
        const int gc = gt_classes[row];
        const float xg = tile[lrow * ROW_STRIDE + gc];
        const float lse = m + __logf(s);
        const float ce  = lse - xg;
        const float pt  = __expf(-ce);
        const float omp = 1.0f - pt;
        focal_t = ALPHA * omp * omp * ce;
    } else if (live && q == 1) {
        // ---------------- GIoU loss ----------------
        const float4 p = ((const float4*)bbox_reg)[row];
        const float4 g = ((const float4*)gt_bboxes)[row];
        const float iw = fmaxf(fminf(p.z, g.z) - fmaxf(p.x, g.x), 0.0f);
        const float ih = fmaxf(fminf(p.w, g.w) - fmaxf(p.y, g.y), 0.0f);
        const float inter  = iw * ih;
        const float area_p = (p.z - p.x) * (p.w - p.y);
        const float area_g = (g.z - g.x) * (g.w - g.y);
        const float uni    = area_p + area_g - inter;
        const float iou    = inter / (uni + EPS_GIOU);
        const float cw = fmaxf(p.z, g.z) - fminf(p.x, g.x);
        const float ch = fmaxf(p.w, g.w) - fminf(p.y, g.y);
        const float area_c = cw * ch;
        const float giou = iou - (area_c - uni) / (area_c + EPS_GIOU);
        giou_t = 1.0f - giou;
    } else if (live && q == 2) {
        // ---------------- centerness: softplus(-c) ----------------
        const float c = centerness[row];
        center_t = fmaxf(-c, 0.0f) + log1pf(__expf(-fabsf(c)));
    }

    // ---------------- block reduction (double, 4 waves) ----------------
    double f = (double)focal_t, gi = (double)giou_t, ce_ = (double)center_t;
    #pragma unroll
    for (int off = 32; off > 0; off >>= 1) {
        f   += __shfl_down(f,   off, 64);
        gi  += __shfl_down(gi,  off, 64);
        ce_ += __shfl_down(ce_, off, 64);
    }
    __shared__ double sf[4], sg[4], sc[4];
    const int lane = t & 63;
    const int wave = t >> 6;
    if (lane == 0) { sf[wave] = f; sg[wave] = gi; sc[wave] = ce_; }
    __syncthreads();
    if (t == 0) {
        partials[blockIdx.x * 3 + 0] = sf[0] + sf[1] + sf[2] + sf[3];
        partials[blockIdx.x * 3 + 1] = sg[0] + sg[1] + sg[2] + sg[3];
        partials[blockIdx.x * 3 + 2] = sc[0] + sc[1] + sc[2] + sc[3];
    }
}

// ---------------------------------------------------------------------------
// Kernel 2: reduce partials, write the 4 output scalars
// ---------------------------------------------------------------------------
__global__ __launch_bounds__(256) void hdm_finalize_kernel(
    const double* __restrict__ partials, int nblocks, int n,
    float* __restrict__ out)
{
    double f = 0.0, g = 0.0, c = 0.0;
    for (int i = threadIdx.x; i < nblocks; i += 256) {
        f += partials[i * 3 + 0];
        g += partials[i * 3 + 1];
        c += partials[i * 3 + 2];
    }
    #pragma unroll
    for (int off = 32; off > 0; off >>= 1) {
        f += __shfl_down(f, off, 64);
        g += __shfl_down(g, off, 64);
        c += __shfl_down(c, off, 64);
    }
    __shared__ double sf[4], sg[4], sc[4];
    const int lane = threadIdx.x & 63;
    const int wave = threadIdx.x >> 6;
    if (lane == 0) { sf[wave] = f; sg[wave] = g; sc[wave] = c; }
    __syncthreads();
    if (threadIdx.x == 0) {
        double tf = 0.0, tg = 0.0, tc = 0.0;
        #pragma unroll
        for (int w = 0; w < 4; ++w) { tf += sf[w]; tg += sg[w]; tc += sc[w]; }
        const double inv_n = 1.0 / (double)n;
        const double focal_mean  = tf * inv_n;
        const double iou_mean    = tg * inv_n;
        const double center_mean = tc * inv_n;
        const double total = focal_mean + iou_mean + (double)CENTER_W * center_mean;
        out[0] = (float)total;
        out[1] = (float)focal_mean;
        out[2] = (float)iou_mean;
        out[3] = (float)center_mean;
    }
}

extern "C" void kernel_launch(void* const* d_in, const int* in_sizes, int n_in,
                              void* d_out, int out_size, void* d_ws, size_t ws_size,
                              hipStream_t stream) {
    const float* cls_logits = (const float*)d_in[0];
    const float* bbox_reg   = (const float*)d_in[1];
    const float* centerness = (const float*)d_in[2];
    const float* gt_bboxes  = (const float*)d_in[3];
    const int*   gt_classes = (const int*)d_in[4];
    float* out = (float*)d_out;

    const int n = in_sizes[2];                                        // N
    const int nblocks = (n + ROWS_PER_BLOCK - 1) / ROWS_PER_BLOCK;    // 15625
    double* partials = (double*)d_ws;                                 // nblocks*3*8B ≈ 375 KB

    hdm_loss_kernel<<<nblocks, THREADS, 0, stream>>>(
        cls_logits, bbox_reg, centerness, gt_bboxes, gt_classes, partials, n);
    hdm_finalize_kernel<<<1, 256, 0, stream>>>(partials, nblocks, n, out);
}

// Round 4
// 443.440 us; speedup vs baseline: 1.1624x; 1.0451x over previous
//
#include <hip/hip_runtime.h>
#include <math.h>

#define NUM_CLASSES 80
#define F4_PER_ROW  20
#define THREADS     256
#define NBLOCKS     4096
#define ROWS_PER_BLOCK_A (THREADS / 4)   // 64 rows per block-iteration (quad per row)

constexpr float ALPHA = 0.25f;
constexpr float CENTER_W = 0.1f;
constexpr float EPS_GIOU = 1e-7f;

typedef float f32x4 __attribute__((ext_vector_type(4)));

// ---------------------------------------------------------------------------
// Kernel 1: LDS-free. Phase A: quad-per-row softmax/focal, row in registers.
//           Phase B: thread-per-row GIoU + centerness (coalesced float4).
// ---------------------------------------------------------------------------
__global__ __launch_bounds__(THREADS) void hdm_loss_kernel(
    const float* __restrict__ cls_logits,   // (N, 80)
    const float* __restrict__ bbox_reg,     // (N, 4)
    const float* __restrict__ centerness,   // (N,)
    const float* __restrict__ gt_bboxes,    // (N, 4)
    const int*   __restrict__ gt_classes,   // (N,)
    double* __restrict__ partials,          // (NBLOCKS, 3)
    int n)
{
    const int t = threadIdx.x;
    double f_acc = 0.0, g_acc = 0.0, c_acc = 0.0;

    // ================= Phase A: focal loss, quad (4 lanes) per row =========
    {
        const int q = t >> 2;          // quad id within block: 0..63
        const int c = t & 3;           // lane within quad
        const f32x4* src = (const f32x4*)cls_logits;

        for (int rb = blockIdx.x * ROWS_PER_BLOCK_A; rb < n;
             rb += NBLOCKS * ROWS_PER_BLOCK_A) {
            const int row = rb + q;
            const bool live = (row < n);

            // each lane: 5 float4 = 20 floats; quad holds the full 80-f row.
            // load j: lane reads f4 index row*20 + j*4 + c -> 64B/quad chunks
            f32x4 v[5];
            const long base = (long)row * F4_PER_ROW + c;
            #pragma unroll
            for (int j = 0; j < 5; ++j) {
                v[j] = live ? __builtin_nontemporal_load(&src[base + j * 4])
                            : (f32x4){0.f, 0.f, 0.f, 0.f};
            }
            const int gc = live ? gt_classes[row] : 0;

            // quad max
            float m = -INFINITY;
            #pragma unroll
            for (int j = 0; j < 5; ++j)
                m = fmaxf(m, fmaxf(fmaxf(v[j].x, v[j].y), fmaxf(v[j].z, v[j].w)));
            m = fmaxf(m, __shfl_xor(m, 1, 64));
            m = fmaxf(m, __shfl_xor(m, 2, 64));

            // quad sum-exp
            float s = 0.0f;
            #pragma unroll
            for (int j = 0; j < 5; ++j) {
                s += __expf(v[j].x - m);
                s += __expf(v[j].y - m);
                s += __expf(v[j].z - m);
                s += __expf(v[j].w - m);
            }
            s += __shfl_xor(s, 1, 64);
            s += __shfl_xor(s, 2, 64);

            // extract x[gc] from registers: owner lane-in-quad = (gc>>2)&3,
            // reg j = gc>>4, component = gc&3. All lanes select their own
            // candidate, then shuffle from the owner.
            const int j_src = gc >> 4;          // 0..4
            const int comp  = gc & 3;
            float sel = 0.0f;
            #pragma unroll
            for (int j = 0; j < 5; ++j) {
                const f32x4 vv = v[j];
                const float cand = (comp == 0) ? vv.x :
                                   (comp == 1) ? vv.y :
                                   (comp == 2) ? vv.z : vv.w;
                sel = (j == j_src) ? cand : sel;
            }
            const int lane = t & 63;
            const float xg = __shfl(sel, (lane & ~3) | ((gc >> 2) & 3), 64);

            if (live && c == 0) {
                const float lse = m + __logf(s);
                const float ce  = lse - xg;
                const float pt  = __expf(-ce);
                const float omp = 1.0f - pt;
                f_acc += (double)(ALPHA * omp * omp * ce);
            }
        }
    }

    // ================= Phase B: GIoU + centerness, thread per row ==========
    {
        const f32x4* pb = (const f32x4*)bbox_reg;
        const f32x4* gb = (const f32x4*)gt_bboxes;
        for (int i = blockIdx.x * THREADS + t; i < n; i += NBLOCKS * THREADS) {
            const f32x4 p = __builtin_nontemporal_load(&pb[i]);
            const f32x4 g = __builtin_nontemporal_load(&gb[i]);
            const float iw = fmaxf(fminf(p.z, g.z) - fmaxf(p.x, g.x), 0.0f);
            const float ih = fmaxf(fminf(p.w, g.w) - fmaxf(p.y, g.y), 0.0f);
            const float inter  = iw * ih;
            const float area_p = (p.z - p.x) * (p.w - p.y);
            const float area_g = (g.z - g.x) * (g.w - g.y);
            const float uni    = area_p + area_g - inter;
            const float iou    = inter / (uni + EPS_GIOU);
            const float cw = fmaxf(p.z, g.z) - fminf(p.x, g.x);
            const float ch = fmaxf(p.w, g.w) - fminf(p.y, g.y);
            const float area_c = cw * ch;
            const float giou = iou - (area_c - uni) / (area_c + EPS_GIOU);
            g_acc += (double)(1.0f - giou);

            const float cc = centerness[i];
            c_acc += (double)(fmaxf(-cc, 0.0f) + log1pf(__expf(-fabsf(cc))));
        }
    }

    // ================= block reduction (double) ============================
    #pragma unroll
    for (int off = 32; off > 0; off >>= 1) {
        f_acc += __shfl_down(f_acc, off, 64);
        g_acc += __shfl_down(g_acc, off, 64);
        c_acc += __shfl_down(c_acc, off, 64);
    }
    __shared__ double sf[4], sg[4], sc[4];
    const int lane = t & 63;
    const int wave = t >> 6;
    if (lane == 0) { sf[wave] = f_acc; sg[wave] = g_acc; sc[wave] = c_acc; }
    __syncthreads();
    if (t == 0) {
        partials[blockIdx.x * 3 + 0] = sf[0] + sf[1] + sf[2] + sf[3];
        partials[blockIdx.x * 3 + 1] = sg[0] + sg[1] + sg[2] + sg[3];
        partials[blockIdx.x * 3 + 2] = sc[0] + sc[1] + sc[2] + sc[3];
    }
}

// ---------------------------------------------------------------------------
// Kernel 2: reduce partials, write the 4 output scalars
// ---------------------------------------------------------------------------
__global__ __launch_bounds__(256) void hdm_finalize_kernel(
    const double* __restrict__ partials, int nblocks, int n,
    float* __restrict__ out)
{
    double f = 0.0, g = 0.0, c = 0.0;
    for (int i = threadIdx.x; i < nblocks; i += 256) {
        f += partials[i * 3 + 0];
        g += partials[i * 3 + 1];
        c += partials[i * 3 + 2];
    }
    #pragma unroll
    for (int off = 32; off > 0; off >>= 1) {
        f += __shfl_down(f, off, 64);
        g += __shfl_down(g, off, 64);
        c += __shfl_down(c, off, 64);
    }
    __shared__ double sf[4], sg[4], sc[4];
    const int lane = threadIdx.x & 63;
    const int wave = threadIdx.x >> 6;
    if (lane == 0) { sf[wave] = f; sg[wave] = g; sc[wave] = c; }
    __syncthreads();
    if (threadIdx.x == 0) {
        double tf = 0.0, tg = 0.0, tc = 0.0;
        #pragma unroll
        for (int w = 0; w < 4; ++w) { tf += sf[w]; tg += sg[w]; tc += sc[w]; }
        const double inv_n = 1.0 / (double)n;
        const double focal_mean  = tf * inv_n;
        const double iou_mean    = tg * inv_n;
        const double center_mean = tc * inv_n;
        const double total = focal_mean + iou_mean + (double)CENTER_W * center_mean;
        out[0] = (float)total;
        out[1] = (float)focal_mean;
        out[2] = (float)iou_mean;
        out[3] = (float)center_mean;
    }
}

extern "C" void kernel_launch(void* const* d_in, const int* in_sizes, int n_in,
                              void* d_out, int out_size, void* d_ws, size_t ws_size,
                              hipStream_t stream) {
    const float* cls_logits = (const float*)d_in[0];
    const float* bbox_reg   = (const float*)d_in[1];
    const float* centerness = (const float*)d_in[2];
    const float* gt_bboxes  = (const float*)d_in[3];
    const int*   gt_classes = (const int*)d_in[4];
    float* out = (float*)d_out;

    const int n = in_sizes[2];              // N
    double* partials = (double*)d_ws;       // NBLOCKS*3*8B = 96 KB

    hdm_loss_kernel<<<NBLOCKS, THREADS, 0, stream>>>(
        cls_logits, bbox_reg, centerness, gt_bboxes, gt_classes, partials, n);
    hdm_finalize_kernel<<<1, 256, 0, stream>>>(partials, NBLOCKS, n, out);
}